// Round 1
// 367.628 us; speedup vs baseline: 1.0028x; 1.0028x over previous
//
#include <hip/hip_runtime.h>

// MeshUnpool: v = zeros(N,C); v[mask_idx] = img; then K sequential copies
//   for s in 0..K-1: k=K-1-s: v[order[1,k]] = v[order[0,k]]
// Step-sequence indexing (s = execution order): f(s)=order[K-1-s], t(s)=order[2K-1-s]
//
// R2 structure (4 dispatches, was 6):
//  k1: inv[0..N)=-1; sparse init LW[t(s)]=-1, head[f(s)]=head[t(s)]=-1 (K-scatter)
//  k2: inv[mask_idx[i]]=i  (M)  ||  atomicMax(LW[t],s) + write-list head/next (K)
//  k3: pure stream  out[row] = inv[row]>=0 ? img[inv[row]] : 0   (the 390 MB pass)
//  k4: sparse fix-up: for surviving steps (s==LW[t(s)]) resolve chain root on the
//      fly via head/next lists (expected list length K/N ~ 0.04) and overwrite row.

__global__ __launch_bounds__(256) void k1_init(const int* __restrict__ order, int K,
                                               int* __restrict__ inv, int* __restrict__ LW,
                                               int* __restrict__ head, int N) {
    int i = blockIdx.x * blockDim.x + threadIdx.x;
    if (i < N) inv[i] = -1;
    if (i < K) {
        int f = order[K - 1 - i];
        int t = order[2 * K - 1 - i];
        LW[t] = -1;          // benign multi-writer: same value
        head[t] = -1;
        head[f] = -1;
    }
}

__global__ __launch_bounds__(256) void k2_build(const int* __restrict__ mask_idx, int M,
                                                const int* __restrict__ order, int K,
                                                int* __restrict__ inv, int* __restrict__ LW,
                                                int* __restrict__ head, int* __restrict__ next) {
    int i = blockIdx.x * blockDim.x + threadIdx.x;
    if (i < M) inv[mask_idx[i]] = i;
    if (i < K) {
        int t = order[2 * K - 1 - i];
        atomicMax(&LW[t], i);
        next[i] = atomicExch(&head[t], i);   // unordered write-list per target vertex
    }
}

// Pure streaming pass: default content for every row. float4-vectorized, coalesced.
__global__ __launch_bounds__(256) void k3_stream(const float4* __restrict__ img4,
                                                 const int* __restrict__ inv,
                                                 float4* __restrict__ out4,
                                                 int N, int c4shift) {
    int C4 = 1 << c4shift;
    long idx = (long)blockIdx.x * blockDim.x + threadIdx.x;
    long row = idx >> c4shift;
    if (row >= N) return;
    int c4 = (int)(idx & (C4 - 1));
    int j = inv[(int)row];
    float4 v = make_float4(0.f, 0.f, 0.f, 0.f);
    if (j >= 0) v = img4[(long)j * C4 + c4];
    out4[idx] = v;
}

// Sparse fix-up: one C4-lane group per step; only the last writer of each target
// row does the copy. Chain-root resolution inline: parent(cur) = max s' < cur
// with t(s')==f(cur), found by scanning f's write-list.
__global__ __launch_bounds__(256) void k4_fix(const int* __restrict__ order, int K,
                                              const int* __restrict__ head,
                                              const int* __restrict__ next,
                                              const int* __restrict__ LW,
                                              const int* __restrict__ inv,
                                              const float4* __restrict__ img4,
                                              float4* __restrict__ out4, int c4shift) {
    int C4 = 1 << c4shift;
    int perBlock = blockDim.x >> c4shift;
    int s = blockIdx.x * perBlock + (threadIdx.x >> c4shift);
    if (s >= K) return;
    int c4 = threadIdx.x & (C4 - 1);
    int t = order[2 * K - 1 - s];
    if (LW[t] != s) return;              // only the surviving (max) writer per row
    int cur = s, src;
    for (;;) {
        int f = order[K - 1 - cur];
        int best = -1;
        for (int nd = head[f]; nd >= 0; nd = next[nd])
            if (nd < cur && nd > best) best = nd;   // last write to f before cur
        if (best < 0) { src = f; break; }           // f untouched before cur: root
        cur = best;                                  // strictly decreasing -> terminates
    }
    int j = inv[src];
    float4 v = make_float4(0.f, 0.f, 0.f, 0.f);
    if (j >= 0) v = img4[(long)j * C4 + c4];
    out4[(long)t * C4 + c4] = v;
}

extern "C" void kernel_launch(void* const* d_in, const int* in_sizes, int n_in,
                              void* d_out, int out_size, void* d_ws, size_t ws_size,
                              hipStream_t stream) {
    const float* img      = (const float*)d_in[0];
    const int*   mask_idx = (const int*)d_in[1];
    const int*   order    = (const int*)d_in[2];
    float*       out      = (float*)d_out;

    const int M  = in_sizes[1];            // 250000
    const int C  = in_sizes[0] / M;        // 128
    const int K  = in_sizes[2] / 2;        // 20000
    const int N  = out_size / C;           // 500000
    const int C4 = C / 4;                  // 32
    int c4shift = 0;
    while ((1 << c4shift) < C4) ++c4shift; // log2(C4); C4 is pow2 here

    int* inv  = (int*)d_ws;                // [N]
    int* LW   = inv + N;                   // [N] (only target entries used)
    int* head = LW + N;                    // [N] (only f/t entries used)
    int* next = head + N;                  // [K]

    const int B = 256;

    k1_init<<<(N + B - 1) / B, B, 0, stream>>>(order, K, inv, LW, head, N);

    int MX = (M > K) ? M : K;
    k2_build<<<(MX + B - 1) / B, B, 0, stream>>>(mask_idx, M, order, K, inv, LW, head, next);

    long total = (long)N << c4shift;       // N * C4 float4 elements
    k3_stream<<<(int)((total + B - 1) / B), B, 0, stream>>>(
        (const float4*)img, inv, (float4*)out, N, c4shift);

    int perBlock = B >> c4shift;           // 8 steps/block at C=128
    k4_fix<<<(K + perBlock - 1) / perBlock, B, 0, stream>>>(
        order, K, head, next, LW, inv, (const float4*)img, (float4*)out, c4shift);
}